// Round 10
// baseline (153.144 us; speedup 1.0000x reference)
//
#include <hip/hip_runtime.h>
#include <hip/hip_bf16.h>

// ProtoNet LOO loss on MI355X — round 10.
// R9 post-mortem: NB=512 cooperative launch exceeded co-resident capacity ->
// runtime rejected the launch silently -> out stayed 0. Lesson: keep grid at
// 256 blocks for cooperative safety.
// R10: R7 structure (padded-line histogram, global list, 2 fence-free
// barriers — best passing config at 44 us) but NT=1024 (16 waves/CU, 1
// block/CU): phase-2 single 8-deep gather batch per thread, phase-B split
// 2 query-halves x 512 classes (2x loads in flight, half FMA per thread).
// logit[q,k] = xq·p[k] - 0.5||p[k]||^2 - 0.5||xq||^2 (non-LOO) with
// closed-form leave-one-out fixup for k* = ys[pos[q]].

#define NQ_ 2048
#define NS_ 65536
#define K_  512
#define D_  128
#define CAP_ 192     // per-class list capacity (actual count is exactly 128)
#define QB_ 8        // queries per block in the loss phase
#define NB_ 256      // grid blocks (1 per CU; cooperative co-residency SAFE)
#define NT_ 1024     // threads per block (16 waves)
#define CSTRIDE_ 32  // counts padded: 1 counter per 128-B line

struct SharedU {
    union {
        struct {
            int   idx[2][CAP_];      // two classes in parallel
            float part[2][16][128];  // 16 row-groups per class (16 KB)
            float red[2][2];
        } proto;
        struct {
            float logit[QB_][K_];    // 16 KB
            float partial[QB_];
        } loss;
    };
};

__device__ inline void st_agent(float* p, float v) {
    __hip_atomic_store(p, v, __ATOMIC_RELAXED, __HIP_MEMORY_SCOPE_AGENT);
}
__device__ inline void st_agent_i(int* p, int v) {
    __hip_atomic_store(p, v, __ATOMIC_RELAXED, __HIP_MEMORY_SCOPE_AGENT);
}

// Fence-free grid barrier (validated R6-R8): all inter-block data is written
// with agent-scope (sc1, write-through) stores; __syncthreads drains vmcnt
// before the leader's arrive-add, so no cache maintenance is needed.
__device__ inline void grid_bar(int* bar, int target) {
    __syncthreads();
    if (threadIdx.x == 0) {
        __hip_atomic_fetch_add(bar, 1, __ATOMIC_RELAXED, __HIP_MEMORY_SCOPE_AGENT);
        while (__hip_atomic_load(bar, __ATOMIC_RELAXED,
                                 __HIP_MEMORY_SCOPE_AGENT) < target) {
            __builtin_amdgcn_s_sleep(1);
        }
    }
    __syncthreads();
}

__device__ inline float logit_of(float dot, float pn, float cnt, float qn, bool loo) {
    if (!loo) {
        if (cnt <= 0.1f) return 0.f;              // mask (C = cnt)
        return dot - 0.5f * pn - 0.5f * qn;
    }
    float cm1 = cnt - 1.f;
    if (cm1 <= 0.1f) return 0.f;                  // mask (C = cnt-1)
    float dotM = cnt * dot;                        // xq·mus
    float msq  = cnt * cnt * pn;                   // ||mus||^2
    float xp   = (dotM - qn) / cm1;                // xq·p_loo
    float plsq = (msq - 2.f * dotM + qn) / (cm1 * cm1);
    return xp - 0.5f * plsq - 0.5f * qn;
}

__launch_bounds__(NT_)
__global__ void fused_kernel(const float* __restrict__ xq,
                             const float* __restrict__ xs,
                             const int* __restrict__ ys,
                             const int* __restrict__ pos,
                             int* __restrict__ countsP,   // padded: idx k*CSTRIDE_
                             int* __restrict__ bar,
                             int* __restrict__ list,
                             float* __restrict__ pnorm,
                             float* __restrict__ pTv,
                             float* __restrict__ out) {
    __shared__ SharedU sh;
    __shared__ float qn_s[QB_];
    __shared__ int   ks_s[QB_];

    int t    = threadIdx.x;                 // 0..1023
    int b    = blockIdx.x;                  // 0..255
    int wave = t >> 6, lane = t & 63;
    int q0   = b * QB_;

    // ---- hoisted phase-B prep + out zero ---------------------------------
    if (wave < QB_) {                       // ||xq||^2 for query q0+wave
        const float* xr = xq + (q0 + wave) * D_;
        float a  = xr[lane];
        float bb = xr[lane + 64];
        float s  = a * a + bb * bb;
        #pragma unroll
        for (int off = 32; off; off >>= 1) s += __shfl_down(s, off, 64);
        if (lane == 0) qn_s[wave] = s;
    }
    if (t < QB_) ks_s[t] = ys[pos[q0 + t]];
    if (t == 0 && b == 0)
        __hip_atomic_store(out, 0.f, __ATOMIC_RELAXED, __HIP_MEMORY_SCOPE_AGENT);

    // ---------------- phase 1: histogram ys -> padded counts + list -------
    // each block owns a 256-element strip (spreads atomic issue over all CUs)
    if (t < 256) {
        int i = b * 256 + t;
        int c = ys[i];
        int slot = atomicAdd(&countsP[c * CSTRIDE_], 1);   // 1 counter per line
        if (slot < CAP_) st_agent_i(&list[c * CAP_ + slot], i);  // sc1 store
    }
    grid_bar(bar, NB_);

    // ---------------- phase 2: prototypes (2 classes x 16 groups) ---------
    {
        int half = t >> 9;             // 0/1 -> class 2b+half
        int tt   = t & 511;
        int d4   = tt & 31;            // float4 index 0..31
        int h    = tt >> 5;            // row-group 0..15
        int k    = 2 * b + half;
        int cnt  = countsP[k * CSTRIDE_];
        int m    = min(cnt, CAP_);
        if (tt < CAP_) sh.proto.idx[half][tt] = (tt < m) ? list[k * CAP_ + tt] : 0;
        __syncthreads();

        const float4* xs4 = (const float4*)xs;
        const int* idx = sh.proto.idx[half];
        int r0 = (m * h) >> 4, r1 = (m * (h + 1)) >> 4;   // ~8 rows each
        float4 acc = make_float4(0.f, 0.f, 0.f, 0.f);
        int r = r0;
        for (; r + 8 <= r1; r += 8) {     // single 8-deep gather batch
            float4 v0 = xs4[idx[r+0] * 32 + d4];
            float4 v1 = xs4[idx[r+1] * 32 + d4];
            float4 v2 = xs4[idx[r+2] * 32 + d4];
            float4 v3 = xs4[idx[r+3] * 32 + d4];
            float4 v4 = xs4[idx[r+4] * 32 + d4];
            float4 v5 = xs4[idx[r+5] * 32 + d4];
            float4 v6 = xs4[idx[r+6] * 32 + d4];
            float4 v7 = xs4[idx[r+7] * 32 + d4];
            acc.x += ((v0.x+v1.x)+(v2.x+v3.x)) + ((v4.x+v5.x)+(v6.x+v7.x));
            acc.y += ((v0.y+v1.y)+(v2.y+v3.y)) + ((v4.y+v5.y)+(v6.y+v7.y));
            acc.z += ((v0.z+v1.z)+(v2.z+v3.z)) + ((v4.z+v5.z)+(v6.z+v7.z));
            acc.w += ((v0.w+v1.w)+(v2.w+v3.w)) + ((v4.w+v5.w)+(v6.w+v7.w));
        }
        for (; r < r1; ++r) {
            float4 v = xs4[idx[r] * 32 + d4];
            acc.x += v.x; acc.y += v.y; acc.z += v.z; acc.w += v.w;
        }
        *(float4*)&sh.proto.part[half][h][d4 * 4] = acc;
        __syncthreads();

        if (t < 256) {
            int hf = t >> 7;           // class half
            int d  = t & 127;          // dim
            int kk = 2 * b + hf;
            float s = 0.f;
            #pragma unroll
            for (int g = 0; g < 16; ++g) s += sh.proto.part[hf][g][d];
            float pv = s / fmaxf((float)countsP[kk * CSTRIDE_], 0.1f);
            // float4-packed transposed store (sc1): comp (d&3) of pTv4[(d>>2)*K_+kk]
            st_agent(&pTv[(d >> 2) * (K_ * 4) + (kk << 2) + (d & 3)], pv);
            float sq = pv * pv;
            #pragma unroll
            for (int off = 32; off; off >>= 1) sq += __shfl_down(sq, off, 64);
            if ((t & 63) == 0) sh.proto.red[hf][d >> 6] = sq;
        }
        __syncthreads();
        if (t < 2) st_agent(&pnorm[2 * b + t], sh.proto.red[t][0] + sh.proto.red[t][1]);
    }
    grid_bar(bar, 2 * NB_);

    // ---------------- phase B: logits + softmax + NLL ---------------------
    {
        // split: tq = t>>9 picks query group (q0+0..3 or q0+4..7), k = t&511.
        // pTv: float4 element d4*K_+k -> 16B/lane coalesced vector loads.
        // xq: wave-uniform addresses -> scalar s_load pipe; loop is pure FMA.
        int tq = t >> 9;
        int k  = t & 511;
        float acc[4];
        #pragma unroll
        for (int q = 0; q < 4; ++q) acc[q] = 0.f;
        const float4* p4 = (const float4*)pTv;
        const float*  xb = xq + (q0 + tq * 4) * D_;
        #pragma unroll 4
        for (int d4 = 0; d4 < D_ / 4; ++d4) {
            float4 pa = p4[d4 * K_ + k];
            #pragma unroll
            for (int q = 0; q < 4; ++q) {
                acc[q] = fmaf(pa.x, xb[q * D_ + 4 * d4 + 0], acc[q]);
                acc[q] = fmaf(pa.y, xb[q * D_ + 4 * d4 + 1], acc[q]);
                acc[q] = fmaf(pa.z, xb[q * D_ + 4 * d4 + 2], acc[q]);
                acc[q] = fmaf(pa.w, xb[q * D_ + 4 * d4 + 3], acc[q]);
            }
        }

        float pn = pnorm[k];
        float cf = (float)countsP[k * CSTRIDE_];
        #pragma unroll
        for (int q = 0; q < 4; ++q) {
            int qq = tq * 4 + q;
            sh.loss.logit[qq][k] = logit_of(acc[q], pn, cf, qn_s[qq], k == ks_s[qq]);
        }
        __syncthreads();

        // softmax + NLL: wave w < QB_ handles query q0+w over 512 logits
        if (wave < QB_) {
            int q = wave;
            float vals[8];
            float vmax = -1e30f;
            #pragma unroll
            for (int j = 0; j < 8; ++j) {
                vals[j] = sh.loss.logit[q][lane + j * 64];
                vmax = fmaxf(vmax, vals[j]);
            }
            #pragma unroll
            for (int off = 32; off; off >>= 1) vmax = fmaxf(vmax, __shfl_xor(vmax, off, 64));
            float se = 0.f;
            #pragma unroll
            for (int j = 0; j < 8; ++j) se += __expf(vals[j] - vmax);
            #pragma unroll
            for (int off = 32; off; off >>= 1) se += __shfl_xor(se, off, 64);
            if (lane == 0) {
                float lse = vmax + __logf(se);        // T = 1.0
                float lk  = sh.loss.logit[q][ks_s[q]];
                sh.loss.partial[q] = lse - lk;        // per-wave partial
            }
        }
        __syncthreads();
        // ONE device atomic per block (256 total)
        if (t == 0) {
            float s = 0.f;
            #pragma unroll
            for (int j = 0; j < QB_; ++j) s += sh.loss.partial[j];
            atomicAdd(out, s * (1.0f / NQ_));
        }
    }
}

// ---------------------------------------------------------------- launch ----
extern "C" void kernel_launch(void* const* d_in, const int* in_sizes, int n_in,
                              void* d_out, int out_size, void* d_ws, size_t ws_size,
                              hipStream_t stream) {
    const float* xq  = (const float*)d_in[0];
    // d_in[1] = yq (unused beyond its length)
    const float* xs  = (const float*)d_in[2];
    const int*   ys  = (const int*)d_in[3];
    const int*   pos = (const int*)d_in[4];
    float* out = (float*)d_out;

    char* ws = (char*)d_ws;
    int*   countsP = (int*)ws;                        // K_ counters, 128 B apart (64 KB)
    int*   bar     = (int*)(ws + 65536);              // barrier counter (own line)
    int*   list    = (int*)(ws + 65536 + 256);        // K_*CAP_ ints
    float* pnorm   = (float*)(ws + 65536 + 256 + K_*CAP_*4);         // K_ f32
    float* pTv     = (float*)(ws + 65536 + 256 + K_*CAP_*4 + 4096);  // D_*K_ f32, f4-packed

    // one memset zeroes padded counts + barrier state (capture-legal)
    hipMemsetAsync(ws, 0, 65536 + 256, stream);

    void* args[] = {(void*)&xq, (void*)&xs, (void*)&ys, (void*)&pos,
                    (void*)&countsP, (void*)&bar, (void*)&list, (void*)&pnorm,
                    (void*)&pTv, (void*)&out};
    hipLaunchCooperativeKernel((const void*)fused_kernel,
                               dim3(NB_), dim3(NT_), args, 0, stream);
}

// Round 11
// 103.795 us; speedup vs baseline: 1.4754x; 1.4754x over previous
//
#include <hip/hip_runtime.h>
#include <hip/hip_bf16.h>

// ProtoNet LOO loss on MI355X — round 11: SPLIT into 3 plain kernels for
// per-phase counters. R10 falsified the occupancy theory (2x waves -> slower);
// the fused kernel hides which phase eats ~40 us of stall. Kernel boundaries
// replace the grid barrier (runtime coherence, no sc1, no cooperative cap).
// logit[q,k] = xq·p[k] - 0.5||p[k]||^2 - 0.5||xq||^2 (non-LOO) with
// closed-form leave-one-out fixup for k* = ys[pos[q]].

#define NQ_ 2048
#define NS_ 65536
#define K_  512
#define D_  128
#define CAP_ 192     // per-class list capacity (actual count is exactly 128)
#define QB_ 4        // queries per block in the loss kernel (512 blocks x 4)
#define CSTRIDE_ 32  // counts padded: 1 counter per 128-B line

// ---------------- K1: histogram -> padded counts + member lists -----------
__global__ void histo_kernel(const int* __restrict__ ys,
                             int* __restrict__ countsP,
                             int* __restrict__ list,
                             float* __restrict__ out) {
    int i = blockIdx.x * 256 + threadIdx.x;    // 256 x 256 = 65536
    if (i == 0) *out = 0.f;                     // zero accumulator for K3
    int c = ys[i];
    int slot = atomicAdd(&countsP[c * CSTRIDE_], 1);   // 1 counter per line
    if (slot < CAP_) list[c * CAP_ + slot] = i;
}

// ---------------- K2: prototypes (1 class per block, grid 512) ------------
__launch_bounds__(512)
__global__ void proto_kernel(const float* __restrict__ xs,
                             const int* __restrict__ countsP,
                             const int* __restrict__ list,
                             float* __restrict__ pTv,
                             float* __restrict__ pnorm) {
    int k = blockIdx.x;            // class id
    int t = threadIdx.x;           // 0..511
    __shared__ int   idx_s[CAP_];
    __shared__ float part_s[16][128];   // 8 KB
    __shared__ float red_s[2];

    int cnt = countsP[k * CSTRIDE_];
    int m = min(cnt, CAP_);
    if (t < CAP_) idx_s[t] = (t < m) ? list[k * CAP_ + t] : 0;
    __syncthreads();

    int d4 = t & 31;               // float4 index 0..31
    int h  = t >> 5;               // row-group 0..15
    const float4* xs4 = (const float4*)xs;
    const int* idx = idx_s;
    int r0 = (m * h) >> 4, r1 = (m * (h + 1)) >> 4;   // ~8 rows each
    float4 acc = make_float4(0.f, 0.f, 0.f, 0.f);
    int r = r0;
    for (; r + 8 <= r1; r += 8) {     // single 8-deep gather batch
        float4 v0 = xs4[idx[r+0] * 32 + d4];
        float4 v1 = xs4[idx[r+1] * 32 + d4];
        float4 v2 = xs4[idx[r+2] * 32 + d4];
        float4 v3 = xs4[idx[r+3] * 32 + d4];
        float4 v4 = xs4[idx[r+4] * 32 + d4];
        float4 v5 = xs4[idx[r+5] * 32 + d4];
        float4 v6 = xs4[idx[r+6] * 32 + d4];
        float4 v7 = xs4[idx[r+7] * 32 + d4];
        acc.x += ((v0.x+v1.x)+(v2.x+v3.x)) + ((v4.x+v5.x)+(v6.x+v7.x));
        acc.y += ((v0.y+v1.y)+(v2.y+v3.y)) + ((v4.y+v5.y)+(v6.y+v7.y));
        acc.z += ((v0.z+v1.z)+(v2.z+v3.z)) + ((v4.z+v5.z)+(v6.z+v7.z));
        acc.w += ((v0.w+v1.w)+(v2.w+v3.w)) + ((v4.w+v5.w)+(v6.w+v7.w));
    }
    for (; r < r1; ++r) {
        float4 v = xs4[idx[r] * 32 + d4];
        acc.x += v.x; acc.y += v.y; acc.z += v.z; acc.w += v.w;
    }
    *(float4*)&part_s[h][d4 * 4] = acc;
    __syncthreads();

    if (t < 128) {
        int d = t;
        float s = 0.f;
        #pragma unroll
        for (int g = 0; g < 16; ++g) s += part_s[g][d];
        float pv = s / fmaxf((float)cnt, 0.1f);
        // float4-packed transposed store: comp (d&3) of pTv4[(d>>2)*K_+k]
        pTv[(d >> 2) * (K_ * 4) + (k << 2) + (d & 3)] = pv;
        float sq = pv * pv;
        #pragma unroll
        for (int off = 32; off; off >>= 1) sq += __shfl_down(sq, off, 64);
        if ((d & 63) == 0) red_s[d >> 6] = sq;
    }
    __syncthreads();
    if (t == 0) pnorm[k] = red_s[0] + red_s[1];
}

// ---------------- K3: logits + softmax + NLL (grid 512, QB=4) -------------
__device__ inline float logit_of(float dot, float pn, float cnt, float qn, bool loo) {
    if (!loo) {
        if (cnt <= 0.1f) return 0.f;              // mask (C = cnt)
        return dot - 0.5f * pn - 0.5f * qn;
    }
    float cm1 = cnt - 1.f;
    if (cm1 <= 0.1f) return 0.f;                  // mask (C = cnt-1)
    float dotM = cnt * dot;                        // xq·mus
    float msq  = cnt * cnt * pn;                   // ||mus||^2
    float xp   = (dotM - qn) / cm1;                // xq·p_loo
    float plsq = (msq - 2.f * dotM + qn) / (cm1 * cm1);
    return xp - 0.5f * plsq - 0.5f * qn;
}

__launch_bounds__(512)
__global__ void loss_kernel(const float* __restrict__ xq,
                            const int* __restrict__ ys,
                            const int* __restrict__ pos,
                            const int* __restrict__ countsP,
                            const float* __restrict__ pTv,
                            const float* __restrict__ pnorm,
                            float* __restrict__ out) {
    __shared__ float logit_s[QB_][K_];   // 8 KB
    __shared__ float qn_s[QB_];
    __shared__ float partial_s[QB_];
    __shared__ int   ks_s[QB_];

    int t    = threadIdx.x;              // 0..511; t == class id
    int wave = t >> 6, lane = t & 63;
    int q0   = blockIdx.x * QB_;         // 512 blocks x 4 queries

    // ||xq||^2: wave w < QB_ reduces query q0+w
    if (wave < QB_) {
        const float* xr = xq + (q0 + wave) * D_;
        float a  = xr[lane];
        float bb = xr[lane + 64];
        float s  = a * a + bb * bb;
        #pragma unroll
        for (int off = 32; off; off >>= 1) s += __shfl_down(s, off, 64);
        if (lane == 0) qn_s[wave] = s;
    }
    if (t < QB_) ks_s[t] = ys[pos[q0 + t]];
    __syncthreads();

    // dot(xq[q], p[k]) for k = t, q = q0..q0+3.
    // pTv: float4 element d4*K_+t -> 16B/lane coalesced vector loads.
    // xq: wave-uniform addresses -> scalar s_load pipe; loop is pure FMA.
    float acc[QB_];
    #pragma unroll
    for (int q = 0; q < QB_; ++q) acc[q] = 0.f;
    const float4* p4 = (const float4*)pTv;
    const float*  xb = xq + q0 * D_;
    #pragma unroll 4
    for (int d4 = 0; d4 < D_ / 4; ++d4) {
        float4 pa = p4[d4 * K_ + t];
        #pragma unroll
        for (int q = 0; q < QB_; ++q) {
            acc[q] = fmaf(pa.x, xb[q * D_ + 4 * d4 + 0], acc[q]);
            acc[q] = fmaf(pa.y, xb[q * D_ + 4 * d4 + 1], acc[q]);
            acc[q] = fmaf(pa.z, xb[q * D_ + 4 * d4 + 2], acc[q]);
            acc[q] = fmaf(pa.w, xb[q * D_ + 4 * d4 + 3], acc[q]);
        }
    }

    float pn = pnorm[t];
    float cf = (float)countsP[t * CSTRIDE_];
    #pragma unroll
    for (int q = 0; q < QB_; ++q)
        logit_s[q][t] = logit_of(acc[q], pn, cf, qn_s[q], t == ks_s[q]);
    __syncthreads();

    // softmax + NLL: wave w < QB_ handles query q0+w over 512 logits
    if (wave < QB_) {
        int q = wave;
        float vals[8];
        float vmax = -1e30f;
        #pragma unroll
        for (int j = 0; j < 8; ++j) {
            vals[j] = logit_s[q][lane + j * 64];
            vmax = fmaxf(vmax, vals[j]);
        }
        #pragma unroll
        for (int off = 32; off; off >>= 1) vmax = fmaxf(vmax, __shfl_xor(vmax, off, 64));
        float se = 0.f;
        #pragma unroll
        for (int j = 0; j < 8; ++j) se += __expf(vals[j] - vmax);
        #pragma unroll
        for (int off = 32; off; off >>= 1) se += __shfl_xor(se, off, 64);
        if (lane == 0) {
            float lse = vmax + __logf(se);        // T = 1.0
            float lk  = logit_s[q][ks_s[q]];
            partial_s[q] = lse - lk;
        }
    }
    __syncthreads();
    // ONE device atomic per block (512 total, distinct arrival times)
    if (t == 0) {
        float s = 0.f;
        #pragma unroll
        for (int j = 0; j < QB_; ++j) s += partial_s[j];
        atomicAdd(out, s * (1.0f / NQ_));
    }
}

// ---------------------------------------------------------------- launch ----
extern "C" void kernel_launch(void* const* d_in, const int* in_sizes, int n_in,
                              void* d_out, int out_size, void* d_ws, size_t ws_size,
                              hipStream_t stream) {
    const float* xq  = (const float*)d_in[0];
    // d_in[1] = yq (unused beyond its length)
    const float* xs  = (const float*)d_in[2];
    const int*   ys  = (const int*)d_in[3];
    const int*   pos = (const int*)d_in[4];
    float* out = (float*)d_out;

    char* ws = (char*)d_ws;
    int*   countsP = (int*)ws;                        // K_ counters, 128 B apart (64 KB)
    int*   list    = (int*)(ws + 65536);              // K_*CAP_ ints
    float* pnorm   = (float*)(ws + 65536 + K_*CAP_*4);          // K_ f32
    float* pTv     = (float*)(ws + 65536 + K_*CAP_*4 + 4096);   // D_*K_ f32, f4-packed

    // zero padded counts (capture-legal)
    hipMemsetAsync(ws, 0, 65536, stream);

    histo_kernel<<<256, 256, 0, stream>>>(ys, countsP, list, out);
    proto_kernel<<<K_, 512, 0, stream>>>(xs, countsP, list, pTv, pnorm);
    loss_kernel<<<NQ_ / QB_, 512, 0, stream>>>(xq, ys, pos, countsP, pTv, pnorm, out);
}